// Round 1
// baseline (710.703 us; speedup 1.0000x reference)
//
#include <hip/hip_runtime.h>

#define KSTATE 64
#define NSAMP  1024

__device__ __forceinline__ float bcast0(float x) {
  return __int_as_float(__builtin_amdgcn_readfirstlane(__float_as_int(x)));
}

// One wave (64 threads): row-softmax of T -> expT, log_softmax(pi) -> log_pi, zero out.
__global__ __launch_bounds__(64) void hmm_preproc(
    const float* __restrict__ pi, const float* __restrict__ T,
    float* __restrict__ expT, float* __restrict__ log_pi,
    float* __restrict__ out) {
  const int lane = threadIdx.x;
  // softmax over row `lane` of T (tiny: 64x64)
  float m = -3.4e38f;
  for (int k = 0; k < KSTATE; ++k) m = fmaxf(m, T[lane * KSTATE + k]);
  float s = 0.f;
  for (int k = 0; k < KSTATE; ++k) s += __expf(T[lane * KSTATE + k] - m);
  float inv = 1.0f / s;
  for (int k = 0; k < KSTATE; ++k)
    expT[lane * KSTATE + k] = __expf(T[lane * KSTATE + k] - m) * inv;
  // log_softmax(pi)
  float x = pi[lane];
  float mm = x;
  #pragma unroll
  for (int off = 32; off >= 1; off >>= 1) mm = fmaxf(mm, __shfl_xor(mm, off, 64));
  float e = __expf(x - mm);
  #pragma unroll
  for (int off = 32; off >= 1; off >>= 1) e += __shfl_xor(e, off, 64);
  log_pi[lane] = x - mm - __logf(e);
  if (lane == 0) out[0] = 0.f;  // harness poisons d_out; we atomicAdd into it
}

// One wave per sequence. Lane k holds alpha[k] and expT column k in registers.
__global__ __launch_bounds__(256) void hmm_forward(
    const float* __restrict__ log_pdf,
    const float* __restrict__ expT,
    const float* __restrict__ log_pi,
    float* __restrict__ out, int N) {
  __shared__ __align__(16) float pbuf[4][KSTATE];  // wave-private p broadcast rows
  const int lane = threadIdx.x & 63;
  const int wave = threadIdx.x >> 6;
  const int b = blockIdx.x * 4 + wave;
  float* pb = pbuf[wave];

  // expT column `lane` into registers: tcol[j] = expT[j][lane]  (coalesced per j)
  float tcol[KSTATE];
  #pragma unroll
  for (int j = 0; j < KSTATE; ++j) tcol[j] = expT[j * KSTATE + lane];

  // lp stream: row `lane`, columns [b*NS, (b+1)*NS). float4 groups of 4 steps.
  const float* lp = log_pdf + (size_t)lane * (size_t)N + (size_t)b * NSAMP;

  float4 cur = *(const float4*)(lp);      // group 0 (t=0..3)
  float4 n1  = *(const float4*)(lp + 4);  // group 1
  float4 n2  = *(const float4*)(lp + 8);  // group 2

  float alpha = cur.x + log_pi[lane];     // t = 0

  // One recurrence step. Wave-private LDS broadcast; within-wave lockstep +
  // explicit lgkmcnt drain makes the write->read ordering safe without s_barrier.
#define STEP(LPV) do {                                                        \
    float c = bcast0(alpha);                                                  \
    float p = __expf(alpha - c);                                              \
    pb[lane] = p;                                                             \
    __asm__ volatile("s_waitcnt lgkmcnt(0)" ::: "memory");                    \
    float s0 = 0.f, s1 = 0.f, s2 = 0.f, s3 = 0.f;                             \
    _Pragma("unroll")                                                         \
    for (int j = 0; j < KSTATE; j += 4) {                                     \
      float4 pv = *(const float4*)(pb + j); /* broadcast read */              \
      s0 = fmaf(pv.x, tcol[j + 0], s0);                                       \
      s1 = fmaf(pv.y, tcol[j + 1], s1);                                       \
      s2 = fmaf(pv.z, tcol[j + 2], s2);                                       \
      s3 = fmaf(pv.w, tcol[j + 3], s3);                                       \
    }                                                                         \
    alpha = (LPV) + c + __logf((s0 + s1) + (s2 + s3));                        \
    __asm__ volatile("" ::: "memory");                                        \
  } while (0)

  // steps t = 1..3 from group 0
  STEP(cur.y); STEP(cur.z); STEP(cur.w);

  // groups 1..255, depth-2 float4 prefetch (~8 steps of lead)
  const int NG = NSAMP / 4;
  for (int g = 1; g < NG; ++g) {
    float4 v = n1; n1 = n2;
    int gn = (g + 2 < NG) ? (g + 2) : (NG - 1);
    n2 = *(const float4*)(lp + 4 * gn);
    STEP(v.x); STEP(v.y); STEP(v.z); STEP(v.w);
  }
#undef STEP

  // final: out += logsumexp_k(alpha)
  float c = bcast0(alpha);
  float e = __expf(alpha - c);
  #pragma unroll
  for (int off = 32; off >= 1; off >>= 1) e += __shfl_xor(e, off, 64);
  if (lane == 0) atomicAdd(out, c + __logf(e));
}

extern "C" void kernel_launch(void* const* d_in, const int* in_sizes, int n_in,
                              void* d_out, int out_size, void* d_ws, size_t ws_size,
                              hipStream_t stream) {
  const float* log_pdf = (const float*)d_in[0];
  const float* pi      = (const float*)d_in[1];
  const float* T       = (const float*)d_in[2];
  float* out = (float*)d_out;

  float* expT   = (float*)d_ws;              // 64*64 floats
  float* log_pi = expT + KSTATE * KSTATE;    // 64 floats

  const int N = in_sizes[0] / KSTATE;        // 1048576
  const int B = N / NSAMP;                   // 1024 sequences

  hipLaunchKernelGGL(hmm_preproc, dim3(1), dim3(64), 0, stream,
                     pi, T, expT, log_pi, out);
  hipLaunchKernelGGL(hmm_forward, dim3(B / 4), dim3(256), 0, stream,
                     log_pdf, expT, log_pi, out, N);
}

// Round 2
// 533.244 us; speedup vs baseline: 1.3328x; 1.3328x over previous
//
#include <hip/hip_runtime.h>

#define KSTATE 64
#define NSAMP  1024

__device__ __forceinline__ float bcast0(float x) {
  return __int_as_float(__builtin_amdgcn_readfirstlane(__float_as_int(x)));
}
__device__ __forceinline__ float rlane(float x, int l) {
  return __int_as_float(__builtin_amdgcn_readlane(__float_as_int(x), l));
}

// One wave (64 threads): row-softmax of T -> expT, log_softmax(pi) -> log_pi, zero out.
__global__ __launch_bounds__(64) void hmm_preproc(
    const float* __restrict__ pi, const float* __restrict__ T,
    float* __restrict__ expT, float* __restrict__ log_pi,
    float* __restrict__ out) {
  const int lane = threadIdx.x;
  float m = -3.4e38f;
  for (int k = 0; k < KSTATE; ++k) m = fmaxf(m, T[lane * KSTATE + k]);
  float s = 0.f;
  for (int k = 0; k < KSTATE; ++k) s += __expf(T[lane * KSTATE + k] - m);
  float inv = 1.0f / s;
  for (int k = 0; k < KSTATE; ++k)
    expT[lane * KSTATE + k] = __expf(T[lane * KSTATE + k] - m) * inv;
  float x = pi[lane];
  float mm = x;
  #pragma unroll
  for (int off = 32; off >= 1; off >>= 1) mm = fmaxf(mm, __shfl_xor(mm, off, 64));
  float e = __expf(x - mm);
  #pragma unroll
  for (int off = 32; off >= 1; off >>= 1) e += __shfl_xor(e, off, 64);
  log_pi[lane] = x - mm - __logf(e);
  if (lane == 0) out[0] = 0.f;  // harness poisons d_out; we atomicAdd into it
}

// One wave per sequence, scaled-linear-domain forward recurrence.
// Lane k holds a[k] (linear alpha, scaled) and expT column k in registers.
// Broadcast of a[j] via v_readlane (constant lane) -> SGPR -> fmac src0.
__global__ __launch_bounds__(256) void hmm_forward(
    const float* __restrict__ log_pdf,
    const float* __restrict__ expT,
    const float* __restrict__ log_pi,
    float* __restrict__ out, int N) {
  const int lane = threadIdx.x & 63;
  const int wave = threadIdx.x >> 6;
  const int b = blockIdx.x * 4 + wave;

  // expT column `lane`: tcol[j] = expT[j][lane]  (coalesced per j)
  float tcol[KSTATE];
  #pragma unroll
  for (int j = 0; j < KSTATE; ++j) tcol[j] = expT[j * KSTATE + lane];

  const float* lp = log_pdf + (size_t)lane * (size_t)N + (size_t)b * NSAMP;

  float4 v0 = *(const float4*)(lp);       // group 0 (t=0..3)
  float4 r1 = *(const float4*)(lp + 4);   // group 1
  float4 r2 = *(const float4*)(lp + 8);   // group 2

  // t = 0: a = exp(lp0 + log_pi - C), C = lane0 shift
  float x0 = v0.x + log_pi[lane];
  float C = bcast0(x0);
  float a = __expf(x0 - C);

  // One recurrence step: s[k] = sum_j a[j]*expT[j][k]; a = elp * s.
#define STEP(ELP) do {                                                        \
    float s0 = 0.f, s1 = 0.f, s2 = 0.f, s3 = 0.f;                             \
    _Pragma("unroll")                                                         \
    for (int j = 0; j < KSTATE; j += 4) {                                     \
      float p0 = rlane(a, j + 0);                                             \
      float p1 = rlane(a, j + 1);                                             \
      float p2 = rlane(a, j + 2);                                             \
      float p3 = rlane(a, j + 3);                                             \
      s0 = fmaf(p0, tcol[j + 0], s0);                                         \
      s1 = fmaf(p1, tcol[j + 1], s1);                                         \
      s2 = fmaf(p2, tcol[j + 2], s2);                                         \
      s3 = fmaf(p3, tcol[j + 3], s3);                                         \
    }                                                                         \
    a = ((s0 + s1) + (s2 + s3)) * (ELP);                                      \
  } while (0)

  // Renorm every 4 steps: fp32 worst-case growth per step <= ~2^14, spread
  // bound min/max >= ~2.5e-14, so 4-step interval stays far inside fp32 range.
#define RENORM() do {                                                         \
    float c = bcast0(a);                                                      \
    a = a * __builtin_amdgcn_rcpf(c);                                         \
    C += __logf(c);                                                           \
  } while (0)

  {  // steps t = 1..3 from group 0
    float e1 = __expf(v0.y), e2 = __expf(v0.z), e3 = __expf(v0.w);
    STEP(e1); STEP(e2); STEP(e3);
    RENORM();
  }

  const int NG = NSAMP / 4;
  for (int g = 1; g < NG; ++g) {
    float4 v = r1; r1 = r2;
    int gn = (g + 2 < NG) ? (g + 2) : (NG - 1);
    r2 = *(const float4*)(lp + 4 * gn);
    float e0 = __expf(v.x), e1 = __expf(v.y), e2 = __expf(v.z), e3 = __expf(v.w);
    STEP(e0); STEP(e1); STEP(e2); STEP(e3);
    RENORM();
  }
#undef STEP
#undef RENORM

  // out += C + log(sum_k a[k])   (spread of a bounded, 64 terms: no overflow)
  float s = a;
  #pragma unroll
  for (int off = 32; off >= 1; off >>= 1) s += __shfl_xor(s, off, 64);
  if (lane == 0) atomicAdd(out, C + __logf(s));
}

extern "C" void kernel_launch(void* const* d_in, const int* in_sizes, int n_in,
                              void* d_out, int out_size, void* d_ws, size_t ws_size,
                              hipStream_t stream) {
  const float* log_pdf = (const float*)d_in[0];
  const float* pi      = (const float*)d_in[1];
  const float* T       = (const float*)d_in[2];
  float* out = (float*)d_out;

  float* expT   = (float*)d_ws;              // 64*64 floats
  float* log_pi = expT + KSTATE * KSTATE;    // 64 floats

  const int N = in_sizes[0] / KSTATE;        // 1048576
  const int B = N / NSAMP;                   // 1024 sequences

  hipLaunchKernelGGL(hmm_preproc, dim3(1), dim3(64), 0, stream,
                     pi, T, expT, log_pi, out);
  hipLaunchKernelGGL(hmm_forward, dim3(B / 4), dim3(256), 0, stream,
                     log_pdf, expT, log_pi, out, N);
}